// Round 1
// baseline (15556.767 us; speedup 1.0000x reference)
//
#include <hip/hip_runtime.h>
#include <hip/hip_cooperative_groups.h>

namespace cg = cooperative_groups;

typedef unsigned short ushort_t;
typedef float  f32x4  __attribute__((ext_vector_type(4)));
typedef __bf16 bf16x8 __attribute__((ext_vector_type(8)));

// Problem sizes (fixed): B=64, S=512, D=1024, H=1024, 4H=4096
#define NB   64
#define NS   512
#define ND   1024
#define NH   1024
#define NG   4096   // 4*H

// ---------- helpers ----------
__device__ __forceinline__ ushort_t f2bf(float f) {
  unsigned u = __float_as_uint(f);
  u += 0x7FFFu + ((u >> 16) & 1u);   // round-to-nearest-even
  return (ushort_t)(u >> 16);
}
__device__ __forceinline__ float bf2f(ushort_t u) {
  return __uint_as_float(((unsigned)u) << 16);
}
__device__ __forceinline__ float sigmoid_f(float x) {
  return 1.0f / (1.0f + __expf(-x));
}
__device__ __forceinline__ float tanh_f(float x) {
  // 1 - 2/(e^{2x}+1): exact limits at +-inf, ~fp32 accurate
  return 1.0f - 2.0f / (__expf(2.0f * x) + 1.0f);
}

// ---------- prep: fp32 -> bf16 conversions ----------
__global__ __launch_bounds__(256) void cvt_x_kernel(const float4* __restrict__ x,
                                                    ushort_t* __restrict__ xb) {
  int i = blockIdx.x * 256 + threadIdx.x;   // exactly NB*NS*ND/4 threads
  float4 v = x[i];
  ushort4 o;
  o.x = f2bf(v.x); o.y = f2bf(v.y); o.z = f2bf(v.z); o.w = f2bf(v.w);
  *(ushort4*)(xb + (size_t)i * 4) = o;
}

__global__ __launch_bounds__(256) void cvt_w_kernel(const float4* __restrict__ W,
                                                    ushort_t* __restrict__ Wx,
                                                    ushort_t* __restrict__ Wh) {
  int i = blockIdx.x * 256 + threadIdx.x;   // exactly NG*(ND+NH)/4 threads
  float4 v = W[i];
  int e = i * 4;
  int n = e >> 11;        // row of W  (2048 cols)
  int c = e & 2047;       // col of W
  ushort4 o;
  o.x = f2bf(v.x); o.y = f2bf(v.y); o.z = f2bf(v.z); o.w = f2bf(v.w);
  ushort_t* dst = (c < ND) ? (Wx + (size_t)n * ND + c)
                           : (Wh + (size_t)n * NH + (c - ND));
  *(ushort4*)dst = o;
}

// ---------- pre-GEMM: PG[t][b][n] = x @ Wx^T + bias  (bf16 out) ----------
// M = B*S = 32768 (m = b*512+t), N = 4096, K = 1024.
// Block = 256 thr (4 waves), tile 128x128; wave tile 64x64 (4x4 frags of 16x16x32).
__global__ __launch_bounds__(256) void pregemm_kernel(
    const ushort_t* __restrict__ xb, const ushort_t* __restrict__ Wx,
    const float* __restrict__ bias, ushort_t* __restrict__ PG) {
  int bid  = blockIdx.x;
  int mblk = bid >> 5;        // 256 m-blocks
  int nblk = bid & 31;        // 32 n-blocks
  int tid  = threadIdx.x;
  int lane = tid & 63, w = tid >> 6;
  int l15  = lane & 15, q = lane >> 4;
  int row0 = mblk * 128 + (w >> 1) * 64;
  int col0 = nblk * 128 + (w & 1) * 64;
  const ushort_t* aBase = xb + (size_t)(row0 + l15) * ND + q * 8;
  const ushort_t* bBase = Wx + (size_t)(col0 + l15) * ND + q * 8;

  f32x4 acc[4][4] = {};
#pragma unroll 2
  for (int k0 = 0; k0 < ND; k0 += 32) {
    bf16x8 a[4], b[4];
#pragma unroll
    for (int mi = 0; mi < 4; ++mi)
      a[mi] = *reinterpret_cast<const bf16x8*>(aBase + (size_t)mi * 16 * ND + k0);
#pragma unroll
    for (int ni = 0; ni < 4; ++ni)
      b[ni] = *reinterpret_cast<const bf16x8*>(bBase + (size_t)ni * 16 * ND + k0);
#pragma unroll
    for (int mi = 0; mi < 4; ++mi)
#pragma unroll
      for (int ni = 0; ni < 4; ++ni)
        acc[mi][ni] = __builtin_amdgcn_mfma_f32_16x16x32_bf16(a[mi], b[ni], acc[mi][ni], 0, 0, 0);
  }
  // C/D layout: col = lane&15, row = q*4 + r
#pragma unroll
  for (int ni = 0; ni < 4; ++ni) {
    int n = col0 + ni * 16 + l15;
    float bv = bias[n];
#pragma unroll
    for (int mi = 0; mi < 4; ++mi) {
#pragma unroll
      for (int r = 0; r < 4; ++r) {
        int m  = row0 + mi * 16 + q * 4 + r;
        int bb = m >> 9;          // batch
        int t  = m & 511;         // time
        PG[((size_t)t * NB + bb) * NG + n] = f2bf(acc[mi][ni][r] + bv);
      }
    }
  }
}

// ---------- recurrent: persistent cooperative kernel ----------
// 64 blocks x 256 thr. Block owns j in [bid*16, bid*16+16).
// Wave w computes gate w tile [64 x 16] = h @ Wh^T slice via 4 MFMA chains.
__global__ __launch_bounds__(256) void lstm_rec_kernel(
    const ushort_t* __restrict__ PG, const ushort_t* __restrict__ Wh,
    ushort_t* hbuf, float* __restrict__ out) {
  cg::grid_group grid = cg::this_grid();
  __shared__ float lds_g[4][64][17];   // +1 pad: kills LDS bank conflicts

  int bid = blockIdx.x;                // 0..63
  int j0  = bid * 16;
  int tid = threadIdx.x;
  int lane = tid & 63, w = tid >> 6;   // wave = gate index (i,f,o,g)
  int l15  = lane & 15, q = lane >> 4;
  int jj   = tid & 15, mrow = tid >> 4;  // cell-phase element mapping

  const ushort_t* bBase = Wh + (size_t)(w * NH + j0 + l15) * NH + q * 8;
  float c_reg[4] = {0.f, 0.f, 0.f, 0.f};  // c owned in registers forever

  for (int t = 0; t < NS; ++t) {
    const ushort_t* hb = hbuf + (size_t)(t & 1) * (NB * NH);
    ushort_t*       hn = hbuf + (size_t)((t & 1) ^ 1) * (NB * NH);

    // prefetch this step's PG values (consumed in cell phase)
    ushort_t pg[4][4];
#pragma unroll
    for (int r = 0; r < 4; ++r) {
      int m = mrow + r * 16;
      const ushort_t* p = PG + ((size_t)t * NB + m) * NG + j0 + jj;
#pragma unroll
      for (int ww = 0; ww < 4; ++ww) pg[r][ww] = p[(size_t)ww * NH];
    }

    // GEMM: gates[m][w*1024 + j0 + l15], m = 0..63
    f32x4 acc[4] = {};
    const ushort_t* aBase = hb + (size_t)l15 * NH + q * 8;
#pragma unroll 2
    for (int k0 = 0; k0 < NH; k0 += 32) {
      bf16x8 bf = *reinterpret_cast<const bf16x8*>(bBase + k0);
      bf16x8 a0 = *reinterpret_cast<const bf16x8*>(aBase + k0);
      bf16x8 a1 = *reinterpret_cast<const bf16x8*>(aBase + 16 * NH + k0);
      bf16x8 a2 = *reinterpret_cast<const bf16x8*>(aBase + 32 * NH + k0);
      bf16x8 a3 = *reinterpret_cast<const bf16x8*>(aBase + 48 * NH + k0);
      acc[0] = __builtin_amdgcn_mfma_f32_16x16x32_bf16(a0, bf, acc[0], 0, 0, 0);
      acc[1] = __builtin_amdgcn_mfma_f32_16x16x32_bf16(a1, bf, acc[1], 0, 0, 0);
      acc[2] = __builtin_amdgcn_mfma_f32_16x16x32_bf16(a2, bf, acc[2], 0, 0, 0);
      acc[3] = __builtin_amdgcn_mfma_f32_16x16x32_bf16(a3, bf, acc[3], 0, 0, 0);
    }

    // exchange gate tiles through LDS (C/D layout: col=l15, row=q*4+r)
#pragma unroll
    for (int mi = 0; mi < 4; ++mi)
#pragma unroll
      for (int r = 0; r < 4; ++r)
        lds_g[w][mi * 16 + q * 4 + r][l15] = acc[mi][r];
    __syncthreads();

    // cell: each thread owns 4 (m, jj) elements, fixed across all steps
#pragma unroll
    for (int r = 0; r < 4; ++r) {
      int m = mrow + r * 16;
      float gi = lds_g[0][m][jj] + bf2f(pg[r][0]);
      float gf = lds_g[1][m][jj] + bf2f(pg[r][1]);
      float go = lds_g[2][m][jj] + bf2f(pg[r][2]);
      float gg = lds_g[3][m][jj] + bf2f(pg[r][3]);
      float cn = sigmoid_f(gf) * c_reg[r] + sigmoid_f(gi) * tanh_f(gg);
      float hv = sigmoid_f(go) * tanh_f(cn);
      c_reg[r] = cn;
      out[(size_t)m * (NS * NH) + (size_t)t * NH + j0 + jj] = hv;
      hn[(size_t)m * NH + j0 + jj] = f2bf(hv);
      if (t == NS - 1) {
        out[(size_t)NB * NS * NH + (size_t)m * NH + j0 + jj] = hv;               // final h
        out[(size_t)NB * NS * NH + (size_t)NB * NH + (size_t)m * NH + j0 + jj] = cn; // final c
      }
    }
    __syncthreads();   // protect lds_g reuse
    grid.sync();       // h visible device-wide before next step
  }
}

// ---------- launch ----------
extern "C" void kernel_launch(void* const* d_in, const int* in_sizes, int n_in,
                              void* d_out, int out_size, void* d_ws, size_t ws_size,
                              hipStream_t stream) {
  const float* x    = (const float*)d_in[0];
  const float* W    = (const float*)d_in[1];
  const float* bias = (const float*)d_in[2];
  float* out = (float*)d_out;

  // workspace layout (bytes), all 16B-aligned
  const size_t off_hbuf = 0;                       // 2 * 64*1024 bf16 = 262144
  const size_t off_Wx   = 262144;                  // 4096*1024 bf16  = 8388608
  const size_t off_Wh   = off_Wx + 8388608;        // 8388608
  const size_t off_xb   = off_Wh + 8388608;        // 32M bf16        = 67108864
  const size_t off_PG   = off_xb + 67108864;       // 512*64*4096 bf16= 268435456
  const size_t need     = off_PG + 268435456;      // ~336.3 MB
  if (ws_size < need) return;  // diagnostic: zero dispatches => ws too small

  char* ws = (char*)d_ws;
  ushort_t* hbuf = (ushort_t*)(ws + off_hbuf);
  ushort_t* Wx   = (ushort_t*)(ws + off_Wx);
  ushort_t* Wh   = (ushort_t*)(ws + off_Wh);
  ushort_t* xb   = (ushort_t*)(ws + off_xb);
  ushort_t* PG   = (ushort_t*)(ws + off_PG);

  // h0 = 0 (both buffers)
  hipMemsetAsync(hbuf, 0, 262144, stream);

  cvt_x_kernel<<<32768, 256, 0, stream>>>((const float4*)x, xb);       // 33554432/4/256
  cvt_w_kernel<<<8192, 256, 0, stream>>>((const float4*)W, Wx, Wh);    //  8388608/4/256
  pregemm_kernel<<<8192, 256, 0, stream>>>(xb, Wx, bias, PG);          // 256 x 32 tiles

  void* args[] = { (void*)&PG, (void*)&Wh, (void*)&hbuf, (void*)&out };
  hipLaunchCooperativeKernel((void*)lstm_rec_kernel, dim3(64), dim3(256),
                             args, 0, stream);
}

// Round 2
// 14682.516 us; speedup vs baseline: 1.0595x; 1.0595x over previous
//
#include <hip/hip_runtime.h>
#include <hip/hip_cooperative_groups.h>

namespace cg = cooperative_groups;

typedef unsigned short ushort_t;
typedef float  f32x4  __attribute__((ext_vector_type(4)));
typedef __bf16 bf16x8 __attribute__((ext_vector_type(8)));

// Problem sizes (fixed): B=64, S=512, D=1024, H=1024, 4H=4096
#define NB   64
#define NS   512
#define ND   1024
#define NH   1024
#define NG   4096   // 4*H
#define HPAD 1032   // 1024 + 8: keeps ds_read_b128 16B-aligned, breaks bank stride

// ---------- helpers ----------
__device__ __forceinline__ ushort_t f2bf(float f) {
  unsigned u = __float_as_uint(f);
  u += 0x7FFFu + ((u >> 16) & 1u);   // round-to-nearest-even
  return (ushort_t)(u >> 16);
}
__device__ __forceinline__ float bf2f(ushort_t u) {
  return __uint_as_float(((unsigned)u) << 16);
}
__device__ __forceinline__ float sigmoid_f(float x) {
  return 1.0f / (1.0f + __expf(-x));
}
__device__ __forceinline__ float tanh_f(float x) {
  return 1.0f - 2.0f / (__expf(2.0f * x) + 1.0f);
}

// ---------- prep: fp32 -> bf16 conversions ----------
__global__ __launch_bounds__(256) void cvt_x_kernel(const float4* __restrict__ x,
                                                    ushort_t* __restrict__ xb) {
  int i = blockIdx.x * 256 + threadIdx.x;
  float4 v = x[i];
  ushort4 o;
  o.x = f2bf(v.x); o.y = f2bf(v.y); o.z = f2bf(v.z); o.w = f2bf(v.w);
  *(ushort4*)(xb + (size_t)i * 4) = o;
}

__global__ __launch_bounds__(256) void cvt_w_kernel(const float4* __restrict__ W,
                                                    ushort_t* __restrict__ Wx,
                                                    ushort_t* __restrict__ Wh) {
  int i = blockIdx.x * 256 + threadIdx.x;
  float4 v = W[i];
  int e = i * 4;
  int n = e >> 11;        // row of W  (2048 cols)
  int c = e & 2047;       // col of W
  ushort4 o;
  o.x = f2bf(v.x); o.y = f2bf(v.y); o.z = f2bf(v.z); o.w = f2bf(v.w);
  ushort_t* dst = (c < ND) ? (Wx + (size_t)n * ND + c)
                           : (Wh + (size_t)n * NH + (c - ND));
  *(ushort4*)dst = o;
}

// ---------- pre-GEMM: PG[t][b][n] = x @ Wx^T + bias  (bf16 out) ----------
__global__ __launch_bounds__(256) void pregemm_kernel(
    const ushort_t* __restrict__ xb, const ushort_t* __restrict__ Wx,
    const float* __restrict__ bias, ushort_t* __restrict__ PG) {
  int bid  = blockIdx.x;
  int mblk = bid >> 5;        // 256 m-blocks
  int nblk = bid & 31;        // 32 n-blocks
  int tid  = threadIdx.x;
  int lane = tid & 63, w = tid >> 6;
  int l15  = lane & 15, q = lane >> 4;
  int row0 = mblk * 128 + (w >> 1) * 64;
  int col0 = nblk * 128 + (w & 1) * 64;
  const ushort_t* aBase = xb + (size_t)(row0 + l15) * ND + q * 8;
  const ushort_t* bBase = Wx + (size_t)(col0 + l15) * ND + q * 8;

  f32x4 acc[4][4] = {};
#pragma unroll 2
  for (int k0 = 0; k0 < ND; k0 += 32) {
    bf16x8 a[4], b[4];
#pragma unroll
    for (int mi = 0; mi < 4; ++mi)
      a[mi] = *reinterpret_cast<const bf16x8*>(aBase + (size_t)mi * 16 * ND + k0);
#pragma unroll
    for (int ni = 0; ni < 4; ++ni)
      b[ni] = *reinterpret_cast<const bf16x8*>(bBase + (size_t)ni * 16 * ND + k0);
#pragma unroll
    for (int mi = 0; mi < 4; ++mi)
#pragma unroll
      for (int ni = 0; ni < 4; ++ni)
        acc[mi][ni] = __builtin_amdgcn_mfma_f32_16x16x32_bf16(a[mi], b[ni], acc[mi][ni], 0, 0, 0);
  }
#pragma unroll
  for (int ni = 0; ni < 4; ++ni) {
    int n = col0 + ni * 16 + l15;
    float bv = bias[n];
#pragma unroll
    for (int mi = 0; mi < 4; ++mi) {
#pragma unroll
      for (int r = 0; r < 4; ++r) {
        int m  = row0 + mi * 16 + q * 4 + r;
        int bb = m >> 9;          // batch
        int t  = m & 511;         // time
        PG[((size_t)t * NB + bb) * NG + n] = f2bf(acc[mi][ni][r] + bv);
      }
    }
  }
}

// ---------- recurrent: persistent cooperative kernel ----------
// 64 blocks x 1024 thr (16 waves). Block owns j in [bid*16, bid*16+16).
// Wave w = (g = w&3, ms = w>>2): computes 16x16 tile of gate g, rows ms*16..+16.
// Full h (64x1024 bf16) staged in LDS each step (coalesced, shared by all waves).
__global__ __launch_bounds__(1024) void lstm_rec_kernel(
    const ushort_t* __restrict__ PG, const ushort_t* __restrict__ Wh,
    ushort_t* hbuf, float* __restrict__ out) {
  cg::grid_group grid = cg::this_grid();
  __shared__ ushort_t lds_h[64 * HPAD];     // 132096 B
  __shared__ float lds_g[4][64][17];        // 17408 B  (total 149504 <= 163840)

  int bid = blockIdx.x;                // 0..63
  int j0  = bid * 16;
  int tid = threadIdx.x;
  int lane = tid & 63, w = tid >> 6;
  int g = w & 3, ms = w >> 2;
  int l15  = lane & 15, q = lane >> 4;
  int jj   = tid & 15, m = tid >> 4;   // cell phase: exactly 1 element/thread

  const ushort_t* bB   = Wh + (size_t)(g * NH + j0 + l15) * NH + q * 8;
  const ushort_t* aRow = lds_h + (size_t)(ms * 16 + l15) * HPAD + q * 8;
  float c_reg = 0.f;                   // c lives in a register for all 512 steps

  for (int t = 0; t < NS; ++t) {
    const ushort_t* hb = hbuf + (size_t)(t & 1) * (NB * NH);
    ushort_t*       hn = hbuf + (size_t)((t & 1) ^ 1) * (NB * NH);

    // PG prefetch: 4 gate pre-activations for this thread's (m, jj)
    const ushort_t* pp = PG + ((size_t)t * NB + m) * NG + j0 + jj;
    ushort_t pg0 = pp[0], pg1 = pp[NH], pg2 = pp[2 * NH], pg3 = pp[3 * NH];

    // stage h into LDS: 8 x 16B per thread, fully coalesced, all independent
#pragma unroll
    for (int it = 0; it < 8; ++it) {
      int e   = it * 8192 + tid * 8;   // element index, 16B chunks
      int row = e >> 10;
      int col = e & 1023;
      uint4 v = *(const uint4*)(hb + e);
      *(uint4*)(lds_h + row * HPAD + col) = v;
    }
    __syncthreads();

    // GEMM: 16x16 tile, single acc chain over K=1024
    f32x4 acc = {};
#pragma unroll 8
    for (int k0 = 0; k0 < NH; k0 += 32) {
      bf16x8 av = *reinterpret_cast<const bf16x8*>(aRow + k0);
      bf16x8 bv = *reinterpret_cast<const bf16x8*>(bB + k0);
      acc = __builtin_amdgcn_mfma_f32_16x16x32_bf16(av, bv, acc, 0, 0, 0);
    }
    // C/D layout: col = lane&15, row = q*4 + r
#pragma unroll
    for (int r = 0; r < 4; ++r)
      lds_g[g][ms * 16 + q * 4 + r][l15] = acc[r];
    __syncthreads();

    // cell: 1 (m, jj) element per thread
    float gi = lds_g[0][m][jj] + bf2f(pg0);
    float gf = lds_g[1][m][jj] + bf2f(pg1);
    float go = lds_g[2][m][jj] + bf2f(pg2);
    float gg = lds_g[3][m][jj] + bf2f(pg3);
    float cn = sigmoid_f(gf) * c_reg + sigmoid_f(gi) * tanh_f(gg);
    float hv = sigmoid_f(go) * tanh_f(cn);
    c_reg = cn;
    out[((size_t)m * NS + t) * NH + j0 + jj] = hv;
    hn[(size_t)m * NH + j0 + jj] = f2bf(hv);
    if (t == NS - 1) {
      out[(size_t)NB * NS * NH + (size_t)m * NH + j0 + jj] = hv;                      // final h
      out[(size_t)NB * NS * NH + (size_t)NB * NH + (size_t)m * NH + j0 + jj] = cn;    // final c
    }
    grid.sync();   // h visible device-wide; also protects lds_h/lds_g reuse
  }
}

// ---------- launch ----------
extern "C" void kernel_launch(void* const* d_in, const int* in_sizes, int n_in,
                              void* d_out, int out_size, void* d_ws, size_t ws_size,
                              hipStream_t stream) {
  const float* x    = (const float*)d_in[0];
  const float* W    = (const float*)d_in[1];
  const float* bias = (const float*)d_in[2];
  float* out = (float*)d_out;

  const size_t off_hbuf = 0;                       // 2 * 64*1024 bf16 = 262144
  const size_t off_Wx   = 262144;                  // 8388608
  const size_t off_Wh   = off_Wx + 8388608;        // 8388608
  const size_t off_xb   = off_Wh + 8388608;        // 67108864
  const size_t off_PG   = off_xb + 67108864;       // 268435456
  const size_t need     = off_PG + 268435456;      // ~336.3 MB
  if (ws_size < need) return;

  char* ws = (char*)d_ws;
  ushort_t* hbuf = (ushort_t*)(ws + off_hbuf);
  ushort_t* Wx   = (ushort_t*)(ws + off_Wx);
  ushort_t* Wh   = (ushort_t*)(ws + off_Wh);
  ushort_t* xb   = (ushort_t*)(ws + off_xb);
  ushort_t* PG   = (ushort_t*)(ws + off_PG);

  hipMemsetAsync(hbuf, 0, 262144, stream);

  cvt_x_kernel<<<32768, 256, 0, stream>>>((const float4*)x, xb);
  cvt_w_kernel<<<8192, 256, 0, stream>>>((const float4*)W, Wx, Wh);
  pregemm_kernel<<<8192, 256, 0, stream>>>(xb, Wx, bias, PG);

  void* args[] = { (void*)&PG, (void*)&Wh, (void*)&hbuf, (void*)&out };
  hipLaunchCooperativeKernel((void*)lstm_rec_kernel, dim3(64), dim3(1024),
                             args, 0, stream);
}